// Round 18
// baseline (173.048 us; speedup 1.0000x reference)
//
#include <hip/hip_runtime.h>
#include <math.h>

#define N_NODES 20000
#define E_EDGES 320000
#define E_TOT   (E_EDGES + N_NODES)   // 340000 (edges + self loops)
#define NEG_SLOPE 0.2f
#define CAP 64                        // per-dst bucket capacity (max deg ~45 here)

#define PREP_TILES 16
#define SCAT_BLKS 1329                // ceil(E_TOT/256)
#define GEMM_BLKS 2504                // 313 m-blocks x 8 heads

typedef __attribute__((ext_vector_type(8))) short bf16x8;
typedef __attribute__((ext_vector_type(4))) float f32x4;

__device__ __forceinline__ float lrelu(float x) { return x > 0.f ? x : NEG_SLOPE * x; }
__device__ __forceinline__ float bflo(unsigned int v) { return __builtin_bit_cast(float, v << 16); }
__device__ __forceinline__ float bfhi(unsigned int v) { return __builtin_bit_cast(float, v & 0xffff0000u); }
__device__ __forceinline__ unsigned int f2bf(float f) {
    return (__builtin_bit_cast(unsigned int, f) + 0x8000u) >> 16;
}

// ---- DIAGNOSTIC SPLIT (r18): scatter+prep in one kernel, gemm pure ----------
// r13-r17: fused gemm_scatter pinned at 50-56 µs, invariant to gemm-half
// restructure, occupancy, conflicts, cursor padding. Model says each half
// should be ~5 µs. Splitting attributes the 50 µs. Harness delivers ALL
// integer inputs as int32 — edge_index is const int*.

__global__ void prep_scatter_k(const float* __restrict__ W1,
                               unsigned short* __restrict__ w1t,
                               const int* __restrict__ ei, int* __restrict__ cursor,
                               int* __restrict__ esorted) {
    __shared__ unsigned short tile[64 * 68];
    int b = blockIdx.x, t = threadIdx.x;
    if (b < PREP_TILES) {
        int k0 = (b & 1) * 64, n0 = (b >> 1) * 64;
        #pragma unroll
        for (int p = 0; p < 16; p++) {       // read coalesced over n
            int k = (t >> 6) + p * 4;
            int n = t & 63;
            tile[k * 68 + n] = (unsigned short)f2bf(W1[(k0 + k) * 512 + n0 + n]);
        }
        __syncthreads();
        #pragma unroll
        for (int p = 0; p < 16; p++) {       // write coalesced over k
            int n = (t >> 6) + p * 4;
            int k = t & 63;
            w1t[(n0 + n) * 128 + k0 + k] = tile[k * 68 + n];
        }
    } else {
        int e = (b - PREP_TILES) * 256 + t;
        if (e < E_TOT) {
            int s, d;
            if (e < E_EDGES) { s = ei[e]; d = ei[E_EDGES + e]; }
            else             { s = e - E_EDGES; d = s; }
            int pos = atomicAdd(&cursor[d], 1);
            if (pos < CAP) esorted[d * CAP + pos] = s;
        }
    }
}

// ---- GEMM1 bf16-MFMA + att1 (HEAD-MAJOR out), pure ---------------------------
// r13 gemm body (LDS As + LDS Bs from prebuilt w1t) + r14 head-major layout.
// head = blockIdx&7 phase-matches agg1 (XCD L2 slice affinity).
// Layouts: Hb[head][node][64] bf16, as_t/ad_t [head][node] fp32.

__global__ __launch_bounds__(256) void gemm_k(
        const float* __restrict__ x, const unsigned short* __restrict__ w1t,
        const float* __restrict__ att_s, const float* __restrict__ att_d,
        unsigned short* __restrict__ Hb,
        float* __restrict__ as_t, float* __restrict__ ad_t) {
    __shared__ unsigned short As[64 * 136];
    __shared__ unsigned short Bs[64 * 136];
    int b = blockIdx.x, t = threadIdx.x;
    int head = b & 7;                    // XCD-phase-matched head
    int m0 = (b >> 3) * 64;
    {   // A stage: 64 rows x 128 fp32 -> bf16, coalesced float4 reads
        int c4 = t & 31;
        int r0 = t >> 5;
        #pragma unroll
        for (int p = 0; p < 8; p++) {
            int row = r0 + p * 8;
            int gm = m0 + row;
            float4 v = make_float4(0.f, 0.f, 0.f, 0.f);
            if (gm < N_NODES) v = ((const float4*)x)[gm * 32 + c4];
            unsigned int lo = f2bf(v.x) | (f2bf(v.y) << 16);
            unsigned int hi = f2bf(v.z) | (f2bf(v.w) << 16);
            *(uint2*)&As[row * 136 + c4 * 4] = make_uint2(lo, hi);
        }
    }
    #pragma unroll
    for (int p = 0; p < 4; p++) {        // B: 64 rows x 16 uint4 = 1024 uint4
        int id = p * 256 + t;
        int row = id >> 4, c16 = id & 15;
        uint4 v = ((const uint4*)w1t)[(head * 64 + row) * 16 + c16];
        *(uint4*)&Bs[row * 136 + c16 * 8] = v;
    }
    __syncthreads();
    int lane = t & 63, w = t >> 6;
    int r = lane & 15, q = lane >> 4;
    f32x4 acc[4] = {{0.f,0.f,0.f,0.f},{0.f,0.f,0.f,0.f},{0.f,0.f,0.f,0.f},{0.f,0.f,0.f,0.f}};
    #pragma unroll
    for (int k0 = 0; k0 < 128; k0 += 32) {
        bf16x8 af = *(const bf16x8*)&As[(w * 16 + r) * 136 + k0 + q * 8];
        #pragma unroll
        for (int nt = 0; nt < 4; nt++) {
            bf16x8 bf = *(const bf16x8*)&Bs[(nt * 16 + r) * 136 + k0 + q * 8];
            acc[nt] = __builtin_amdgcn_mfma_f32_16x16x32_bf16(af, bf, acc[nt], 0, 0, 0);
        }
    }
    float sa[4], da[4];
    #pragma unroll
    for (int nt = 0; nt < 4; nt++) {
        sa[nt] = att_s[head * 64 + nt * 16 + r];
        da[nt] = att_d[head * 64 + nt * 16 + r];
    }
    #pragma unroll
    for (int i = 0; i < 4; i++) {
        int m = m0 + w * 16 + q * 4 + i;
        float ps = acc[0][i]*sa[0] + acc[1][i]*sa[1] + acc[2][i]*sa[2] + acc[3][i]*sa[3];
        float pd = acc[0][i]*da[0] + acc[1][i]*da[1] + acc[2][i]*da[2] + acc[3][i]*da[3];
        ps += __shfl_xor(ps, 1); ps += __shfl_xor(ps, 2);
        ps += __shfl_xor(ps, 4); ps += __shfl_xor(ps, 8);
        pd += __shfl_xor(pd, 1); pd += __shfl_xor(pd, 2);
        pd += __shfl_xor(pd, 4); pd += __shfl_xor(pd, 8);
        if (m < N_NODES) {
            if (r == 0) { as_t[head * N_NODES + m] = ps; ad_t[head * N_NODES + m] = pd; }
            #pragma unroll
            for (int nt = 0; nt < 4; nt++) {
                float v = acc[nt][i];
                float vn = __shfl_xor(v, 1);       // neighbor col
                if ((r & 1) == 0) {
                    unsigned int pk = f2bf(v) | (f2bf(vn) << 16);
                    *(unsigned int*)&Hb[((size_t)head * N_NODES + m) * 64 + nt * 16 + r] = pk;
                }
            }
        }
    }
}

// ---- layer-1 aggregation: 8-lane OCTET = one (node, head) -------------------
// (r14/r17 form — agg1 below top-5 at <48 µs) head = blockIdx&7 XCD affinity.

__global__ __launch_bounds__(256) void agg1_k(const uint4* __restrict__ hu4,
                                              const float* __restrict__ as_t,
                                              const float* __restrict__ ad_t,
                                              const int* __restrict__ cnt,
                                              const int* __restrict__ esorted,
                                              const float* __restrict__ b1,
                                              const float* __restrict__ W2,
                                              float* __restrict__ p2acc) {
    int b = blockIdx.x, t = threadIdx.x;
    int head = b & 7;
    int chunk = b >> 3;                  // 0..624
    int lane = t & 63, wv = t >> 6;
    int oct = lane >> 3, sl = lane & 7;
    int i = chunk * 32 + wv * 8 + oct;   // node, exact cover of [0,20000)
    int deg = min(cnt[i], CAP);
    float adh = ad_t[head * N_NODES + i];
    const float* asb = as_t + head * N_NODES;
    const uint4* hb = hu4 + (size_t)head * N_NODES * 8;
    float acc[8] = {0.f, 0.f, 0.f, 0.f, 0.f, 0.f, 0.f, 0.f};
    float dsum = 0.f;
    for (int base = 0; base < deg; base += 8) {
        int slot = base + sl;
        int s = (slot < deg) ? esorted[(i << 6) + slot] : 0;
        float cf = 0.f;
        if (slot < deg) cf = __expf(lrelu(asb[s] + adh));
        dsum += cf;
        #pragma unroll
        for (int j = 0; j < 8; j++) {
            int sj = __shfl(s, oct * 8 + j);
            float cj = __shfl(cf, oct * 8 + j);
            uint4 v = hb[sj * 8 + sl];
            acc[0] += cj * bflo(v.x); acc[1] += cj * bfhi(v.x);
            acc[2] += cj * bflo(v.y); acc[3] += cj * bfhi(v.y);
            acc[4] += cj * bflo(v.z); acc[5] += cj * bfhi(v.z);
            acc[6] += cj * bflo(v.w); acc[7] += cj * bfhi(v.w);
        }
    }
    dsum += __shfl_xor(dsum, 1);
    dsum += __shfl_xor(dsum, 2);
    dsum += __shfl_xor(dsum, 4);         // full denominator for (i, head)
    float inv = 1.f / dsum;
    int colb = head * 64 + sl * 8;
    float4 bA = *(const float4*)&b1[colb];
    float4 bB = *(const float4*)&b1[colb + 4];
    float bb[8] = {bA.x, bA.y, bA.z, bA.w, bB.x, bB.y, bB.z, bB.w};
    float p0 = 0.f, p1 = 0.f;
    #pragma unroll
    for (int j = 0; j < 8; j++) {
        float vg = acc[j] * inv + bb[j];
        vg = vg > 0.f ? vg : expm1f(vg);
        p0 += vg * W2[(colb + j) * 2];
        p1 += vg * W2[(colb + j) * 2 + 1];
    }
    p0 += __shfl_xor(p0, 1); p0 += __shfl_xor(p0, 2); p0 += __shfl_xor(p0, 4);
    p1 += __shfl_xor(p1, 1); p1 += __shfl_xor(p1, 2); p1 += __shfl_xor(p1, 4);
    if (sl == 0) {
        atomicAdd(&p2acc[i * 2],     p0);
        atomicAdd(&p2acc[i * 2 + 1], p1);
    }
}

// ---- layer-2 softmax + aggregation: 8-lane octet per dst node ---------------
// p2acc[s] = (h2c0, h2c1); a2s/a2d recomputed inline (2 FMA/edge).

__global__ void agg2_k(const float2* __restrict__ p2acc, const int* __restrict__ cnt,
                       const int* __restrict__ esorted, const float* __restrict__ as2,
                       const float* __restrict__ ad2, const float* __restrict__ b2,
                       float* __restrict__ out) {
    int gid = blockIdx.x * blockDim.x + threadIdx.x;
    int wv = gid >> 6;
    int lane = threadIdx.x & 63;
    int g = lane >> 3, sl = lane & 7;
    int i = wv * 8 + g;
    if (i >= N_NODES) return;
    float s0 = as2[0], s1 = as2[1], d0 = ad2[0], d1 = ad2[1];
    float2 ci = p2acc[i];
    float adi = ci.x * d0 + ci.y * d1;
    int deg = min(cnt[i], CAP);
    float lsum = 0.f, o0 = 0.f, o1 = 0.f;
    for (int e = sl; e < deg; e += 8) {
        int s = esorted[(i << 6) + e];
        float2 cs = p2acc[s];
        float ex = __expf(lrelu(cs.x * s0 + cs.y * s1 + adi));
        lsum += ex;
        o0 += ex * cs.x;
        o1 += ex * cs.y;
    }
    #pragma unroll
    for (int m = 1; m < 8; m <<= 1) {
        lsum += __shfl_xor(lsum, m);
        o0 += __shfl_xor(o0, m);
        o1 += __shfl_xor(o1, m);
    }
    if (sl == 0) {
        float inv = 1.f / lsum;
        out[i * 2]     = o0 * inv + b2[0];
        out[i * 2 + 1] = o1 * inv + b2[1];
    }
}

// ---------------- launch ----------------

extern "C" void kernel_launch(void* const* d_in, const int* in_sizes, int n_in,
                              void* d_out, int out_size, void* d_ws, size_t ws_size,
                              hipStream_t stream) {
    const float* x        = (const float*)d_in[0];
    const int*   ei       = (const int*)d_in[1];    // int32 per harness contract
    const float* W1       = (const float*)d_in[2];
    const float* att_src1 = (const float*)d_in[3];
    const float* att_dst1 = (const float*)d_in[4];
    const float* b1       = (const float*)d_in[5];
    const float* W2       = (const float*)d_in[6];
    const float* att_src2 = (const float*)d_in[7];
    const float* att_dst2 = (const float*)d_in[8];
    const float* b2       = (const float*)d_in[9];
    float* out = (float*)d_out;

    // workspace layout (~27 MB)
    unsigned short* h1b = (unsigned short*)d_ws;         // [8][20000][64] bf16
    unsigned short* w1t = h1b + (size_t)N_NODES * 512;   // 512*128 bf16
    float* as_t = (float*)(w1t + 512 * 128);             // [8][20000]
    float* ad_t = as_t + 8 * N_NODES;                    // [8][20000]
    int* cursor  = (int*)(ad_t + 8 * N_NODES);           // 20000  <- memset...
    float* p2acc = (float*)(cursor + N_NODES);           // 20000*2 <- ...to here
    int* esorted = (int*)(p2acc + 2 * N_NODES);          // 20000*64

    hipMemsetAsync(cursor, 0, 3 * N_NODES * sizeof(int), stream);  // cursor+p2acc

    prep_scatter_k<<<PREP_TILES + SCAT_BLKS, 256, 0, stream>>>(
        W1, w1t, ei, cursor, esorted);

    gemm_k<<<GEMM_BLKS, 256, 0, stream>>>(x, w1t, att_src1, att_dst1,
                                          h1b, as_t, ad_t);

    agg1_k<<<5000, 256, 0, stream>>>((const uint4*)h1b, as_t, ad_t, cursor,
                                     esorted, b1, W2, p2acc);

    agg2_k<<<(N_NODES / 8 * 64 + 255) / 256, 256, 0, stream>>>(
        (const float2*)p2acc, cursor, esorted, att_src2, att_dst2, b2, out);
}

// Round 19
// 167.140 us; speedup vs baseline: 1.0353x; 1.0353x over previous
//
#include <hip/hip_runtime.h>
#include <math.h>

#define N_NODES 20000
#define E_EDGES 320000
#define E_TOT   (E_EDGES + N_NODES)   // 340000 (edges + self loops)
#define NEG_SLOPE 0.2f
#define CAP 64                        // per-dst bucket capacity (max deg ~45 here)

#define PREP_TILES 16
#define ZERO_BLKS 59                  // 60000 words (cursor+p2acc) as uint4
#define SCAT_BLKS 1329                // ceil(E_TOT/256)
#define GEMM_BLKS 2504                // 313 m-blocks x 8 heads

typedef __attribute__((ext_vector_type(8))) short bf16x8;
typedef __attribute__((ext_vector_type(4))) float f32x4;

__device__ __forceinline__ float lrelu(float x) { return x > 0.f ? x : NEG_SLOPE * x; }
__device__ __forceinline__ float bflo(unsigned int v) { return __builtin_bit_cast(float, v << 16); }
__device__ __forceinline__ float bfhi(unsigned int v) { return __builtin_bit_cast(float, v & 0xffff0000u); }
__device__ __forceinline__ unsigned int f2bf(float f) {
    return (__builtin_bit_cast(unsigned int, f) + 0x8000u) >> 16;
}

// ---- prep: W1^T bf16 (LDS-transposed) | zero cursor+p2acc (memset folded) ---

__global__ void prep_k(const float* __restrict__ W1, unsigned short* __restrict__ w1t,
                       uint4* __restrict__ zbase) {
    __shared__ unsigned short tile[64 * 68];
    int b = blockIdx.x, t = threadIdx.x;
    if (b >= PREP_TILES) {               // zero cursor (20000 ints) + p2acc (40000 f32)
        int idx = (b - PREP_TILES) * 256 + t;
        if (idx < 15000) zbase[idx] = make_uint4(0u, 0u, 0u, 0u);
        return;
    }
    int k0 = (b & 1) * 64, n0 = (b >> 1) * 64;
    #pragma unroll
    for (int p = 0; p < 16; p++) {       // read coalesced over n
        int k = (t >> 6) + p * 4;
        int n = t & 63;
        tile[k * 68 + n] = (unsigned short)f2bf(W1[(k0 + k) * 512 + n0 + n]);
    }
    __syncthreads();
    #pragma unroll
    for (int p = 0; p < 16; p++) {       // write coalesced over k
        int n = (t >> 6) + p * 4;
        int k = t & 63;
        w1t[(n0 + n) * 128 + k0 + k] = tile[k * 68 + n];
    }
}

// ---- FUSED: bucket scatter + GEMM1 bf16-MFMA + att1 (HEAD-MAJOR out) --------
// r17 best-measured config (168.5 µs total). Scatter: fixed 64-slot buckets,
// unpadded cursor (r16: line-padding neutral). GEMM: r13 body (LDS As + LDS
// Bs uint4-staged from prebuilt w1t — 800K conflicts; r14 in-block transpose
// 5.3M, r15 B-in-registers re-read 160 MB L2) + r14 head-major layout
// (head = blockIdx&7; all agg1 readers of one head slice land on one XCD,
// slice 2.56 MB < 4 MB L2). r18 split showed both halves <47 µs — the 50 µs
// is a genuine sum, keep fused for overlap.
// Layouts: Hb[head][node][64] bf16, as_t/ad_t [head][node] fp32.
// Harness delivers ALL integer inputs as int32 — edge_index is const int*.

__global__ __launch_bounds__(256) void gemm_scatter_k(
        const float* __restrict__ x, const unsigned short* __restrict__ w1t,
        const float* __restrict__ att_s, const float* __restrict__ att_d,
        const int* __restrict__ ei, int* __restrict__ cursor,
        int* __restrict__ esorted, unsigned short* __restrict__ Hb,
        float* __restrict__ as_t, float* __restrict__ ad_t) {
    __shared__ unsigned short As[64 * 136];
    __shared__ unsigned short Bs[64 * 136];
    int b = blockIdx.x, t = threadIdx.x;
    if (b < SCAT_BLKS) {                 // ---- scatter part ----
        int e = b * 256 + t;
        if (e < E_TOT) {
            int s, d;
            if (e < E_EDGES) { s = ei[e]; d = ei[E_EDGES + e]; }
            else             { s = e - E_EDGES; d = s; }
            int pos = atomicAdd(&cursor[d], 1);
            if (pos < CAP) esorted[d * CAP + pos] = s;
        }
        return;
    }
    // ---- gemm part ----
    int head = b & 7;                    // XCD-phase-matched head
    int m0 = ((b - SCAT_BLKS) >> 3) * 64;
    {   // A stage: 64 rows x 128 fp32 -> bf16, coalesced float4 reads
        int c4 = t & 31;
        int r0 = t >> 5;
        #pragma unroll
        for (int p = 0; p < 8; p++) {
            int row = r0 + p * 8;
            int gm = m0 + row;
            float4 v = make_float4(0.f, 0.f, 0.f, 0.f);
            if (gm < N_NODES) v = ((const float4*)x)[gm * 32 + c4];
            unsigned int lo = f2bf(v.x) | (f2bf(v.y) << 16);
            unsigned int hi = f2bf(v.z) | (f2bf(v.w) << 16);
            *(uint2*)&As[row * 136 + c4 * 4] = make_uint2(lo, hi);
        }
    }
    #pragma unroll
    for (int p = 0; p < 4; p++) {        // B: 64 rows x 16 uint4 = 1024 uint4
        int id = p * 256 + t;
        int row = id >> 4, c16 = id & 15;
        uint4 v = ((const uint4*)w1t)[(head * 64 + row) * 16 + c16];
        *(uint4*)&Bs[row * 136 + c16 * 8] = v;
    }
    __syncthreads();
    int lane = t & 63, w = t >> 6;
    int r = lane & 15, q = lane >> 4;
    f32x4 acc[4] = {{0.f,0.f,0.f,0.f},{0.f,0.f,0.f,0.f},{0.f,0.f,0.f,0.f},{0.f,0.f,0.f,0.f}};
    #pragma unroll
    for (int k0 = 0; k0 < 128; k0 += 32) {
        bf16x8 af = *(const bf16x8*)&As[(w * 16 + r) * 136 + k0 + q * 8];
        #pragma unroll
        for (int nt = 0; nt < 4; nt++) {
            bf16x8 bf = *(const bf16x8*)&Bs[(nt * 16 + r) * 136 + k0 + q * 8];
            acc[nt] = __builtin_amdgcn_mfma_f32_16x16x32_bf16(af, bf, acc[nt], 0, 0, 0);
        }
    }
    float sa[4], da[4];
    #pragma unroll
    for (int nt = 0; nt < 4; nt++) {
        sa[nt] = att_s[head * 64 + nt * 16 + r];
        da[nt] = att_d[head * 64 + nt * 16 + r];
    }
    #pragma unroll
    for (int i = 0; i < 4; i++) {
        int m = m0 + w * 16 + q * 4 + i;
        float ps = acc[0][i]*sa[0] + acc[1][i]*sa[1] + acc[2][i]*sa[2] + acc[3][i]*sa[3];
        float pd = acc[0][i]*da[0] + acc[1][i]*da[1] + acc[2][i]*da[2] + acc[3][i]*da[3];
        ps += __shfl_xor(ps, 1); ps += __shfl_xor(ps, 2);
        ps += __shfl_xor(ps, 4); ps += __shfl_xor(ps, 8);
        pd += __shfl_xor(pd, 1); pd += __shfl_xor(pd, 2);
        pd += __shfl_xor(pd, 4); pd += __shfl_xor(pd, 8);
        if (m < N_NODES) {
            if (r == 0) { as_t[head * N_NODES + m] = ps; ad_t[head * N_NODES + m] = pd; }
            #pragma unroll
            for (int nt = 0; nt < 4; nt++) {
                float v = acc[nt][i];
                float vn = __shfl_xor(v, 1);       // neighbor col
                if ((r & 1) == 0) {
                    unsigned int pk = f2bf(v) | (f2bf(vn) << 16);
                    *(unsigned int*)&Hb[((size_t)head * N_NODES + m) * 64 + nt * 16 + r] = pk;
                }
            }
        }
    }
}

// ---- layer-1 aggregation: 8-lane OCTET = one (node, head) -------------------
// Block's head = blockIdx&7: all readers of one head's 2.56 MB slice land on
// one XCD -> L2-resident gathers. Per edge: octet gathers the 128 B head-row
// (8 x uint4). Denominator: per-lane partial + 3 octet shfl_xor. Epilogue:
// per-head bias+ELU+W2 partial projection, atomicAdd into p2acc[node]
// (zeroed in prep_k).

__global__ __launch_bounds__(256) void agg1_k(const uint4* __restrict__ hu4,
                                              const float* __restrict__ as_t,
                                              const float* __restrict__ ad_t,
                                              const int* __restrict__ cnt,
                                              const int* __restrict__ esorted,
                                              const float* __restrict__ b1,
                                              const float* __restrict__ W2,
                                              float* __restrict__ p2acc) {
    int b = blockIdx.x, t = threadIdx.x;
    int head = b & 7;
    int chunk = b >> 3;                  // 0..624
    int lane = t & 63, wv = t >> 6;
    int oct = lane >> 3, sl = lane & 7;
    int i = chunk * 32 + wv * 8 + oct;   // node, exact cover of [0,20000)
    int deg = min(cnt[i], CAP);
    float adh = ad_t[head * N_NODES + i];
    const float* asb = as_t + head * N_NODES;
    const uint4* hb = hu4 + (size_t)head * N_NODES * 8;
    float acc[8] = {0.f, 0.f, 0.f, 0.f, 0.f, 0.f, 0.f, 0.f};
    float dsum = 0.f;
    for (int base = 0; base < deg; base += 8) {
        int slot = base + sl;
        int s = (slot < deg) ? esorted[(i << 6) + slot] : 0;
        float cf = 0.f;
        if (slot < deg) cf = __expf(lrelu(asb[s] + adh));
        dsum += cf;
        #pragma unroll
        for (int j = 0; j < 8; j++) {
            int sj = __shfl(s, oct * 8 + j);
            float cj = __shfl(cf, oct * 8 + j);
            uint4 v = hb[sj * 8 + sl];
            acc[0] += cj * bflo(v.x); acc[1] += cj * bfhi(v.x);
            acc[2] += cj * bflo(v.y); acc[3] += cj * bfhi(v.y);
            acc[4] += cj * bflo(v.z); acc[5] += cj * bfhi(v.z);
            acc[6] += cj * bflo(v.w); acc[7] += cj * bfhi(v.w);
        }
    }
    dsum += __shfl_xor(dsum, 1);
    dsum += __shfl_xor(dsum, 2);
    dsum += __shfl_xor(dsum, 4);         // full denominator for (i, head)
    float inv = 1.f / dsum;
    int colb = head * 64 + sl * 8;
    float4 bA = *(const float4*)&b1[colb];
    float4 bB = *(const float4*)&b1[colb + 4];
    float bb[8] = {bA.x, bA.y, bA.z, bA.w, bB.x, bB.y, bB.z, bB.w};
    float p0 = 0.f, p1 = 0.f;
    #pragma unroll
    for (int j = 0; j < 8; j++) {
        float vg = acc[j] * inv + bb[j];
        vg = vg > 0.f ? vg : expm1f(vg);
        p0 += vg * W2[(colb + j) * 2];
        p1 += vg * W2[(colb + j) * 2 + 1];
    }
    p0 += __shfl_xor(p0, 1); p0 += __shfl_xor(p0, 2); p0 += __shfl_xor(p0, 4);
    p1 += __shfl_xor(p1, 1); p1 += __shfl_xor(p1, 2); p1 += __shfl_xor(p1, 4);
    if (sl == 0) {
        atomicAdd(&p2acc[i * 2],     p0);
        atomicAdd(&p2acc[i * 2 + 1], p1);
    }
}

// ---- layer-2 softmax + aggregation: 8-lane octet per dst node ---------------
// p2acc[s] = (h2c0, h2c1); a2s/a2d recomputed inline (2 FMA/edge).

__global__ void agg2_k(const float2* __restrict__ p2acc, const int* __restrict__ cnt,
                       const int* __restrict__ esorted, const float* __restrict__ as2,
                       const float* __restrict__ ad2, const float* __restrict__ b2,
                       float* __restrict__ out) {
    int gid = blockIdx.x * blockDim.x + threadIdx.x;
    int wv = gid >> 6;
    int lane = threadIdx.x & 63;
    int g = lane >> 3, sl = lane & 7;
    int i = wv * 8 + g;
    if (i >= N_NODES) return;
    float s0 = as2[0], s1 = as2[1], d0 = ad2[0], d1 = ad2[1];
    float2 ci = p2acc[i];
    float adi = ci.x * d0 + ci.y * d1;
    int deg = min(cnt[i], CAP);
    float lsum = 0.f, o0 = 0.f, o1 = 0.f;
    for (int e = sl; e < deg; e += 8) {
        int s = esorted[(i << 6) + e];
        float2 cs = p2acc[s];
        float ex = __expf(lrelu(cs.x * s0 + cs.y * s1 + adi));
        lsum += ex;
        o0 += ex * cs.x;
        o1 += ex * cs.y;
    }
    #pragma unroll
    for (int m = 1; m < 8; m <<= 1) {
        lsum += __shfl_xor(lsum, m);
        o0 += __shfl_xor(o0, m);
        o1 += __shfl_xor(o1, m);
    }
    if (sl == 0) {
        float inv = 1.f / lsum;
        out[i * 2]     = o0 * inv + b2[0];
        out[i * 2 + 1] = o1 * inv + b2[1];
    }
}

// ---------------- launch ----------------

extern "C" void kernel_launch(void* const* d_in, const int* in_sizes, int n_in,
                              void* d_out, int out_size, void* d_ws, size_t ws_size,
                              hipStream_t stream) {
    const float* x        = (const float*)d_in[0];
    const int*   ei       = (const int*)d_in[1];    // int32 per harness contract
    const float* W1       = (const float*)d_in[2];
    const float* att_src1 = (const float*)d_in[3];
    const float* att_dst1 = (const float*)d_in[4];
    const float* b1       = (const float*)d_in[5];
    const float* W2       = (const float*)d_in[6];
    const float* att_src2 = (const float*)d_in[7];
    const float* att_dst2 = (const float*)d_in[8];
    const float* b2       = (const float*)d_in[9];
    float* out = (float*)d_out;

    // workspace layout (~27 MB; all segment offsets 16B-aligned)
    unsigned short* h1b = (unsigned short*)d_ws;         // [8][20000][64] bf16
    unsigned short* w1t = h1b + (size_t)N_NODES * 512;   // 512*128 bf16
    float* as_t = (float*)(w1t + 512 * 128);             // [8][20000]
    float* ad_t = as_t + 8 * N_NODES;                    // [8][20000]
    int* cursor  = (int*)(ad_t + 8 * N_NODES);           // 20000  <- zeroed in prep_k
    float* p2acc = (float*)(cursor + N_NODES);           // 20000*2 <- zeroed in prep_k
    int* esorted = (int*)(p2acc + 2 * N_NODES);          // 20000*64

    prep_k<<<PREP_TILES + ZERO_BLKS, 256, 0, stream>>>(W1, w1t, (uint4*)cursor);

    gemm_scatter_k<<<SCAT_BLKS + GEMM_BLKS, 256, 0, stream>>>(
        x, w1t, att_src1, att_dst1, ei, cursor, esorted, h1b, as_t, ad_t);

    agg1_k<<<5000, 256, 0, stream>>>((const uint4*)h1b, as_t, ad_t, cursor,
                                     esorted, b1, W2, p2acc);

    agg2_k<<<(N_NODES / 8 * 64 + 255) / 256, 256, 0, stream>>>(
        (const float2*)p2acc, cursor, esorted, att_src2, att_dst2, b2, out);
}